// Round 1
// baseline (202.020 us; speedup 1.0000x reference)
//
#include <hip/hip_runtime.h>
#include <hip/hip_bf16.h>

// ---------------------------------------------------------------------------
// Causal MHA forward.  B=2, T=2048, H=16, Dk=64, D=1024.  Inputs float32;
// internal pipeline bf16 MFMA.
// R13: attn rewritten as double-buffered KVBLK=64 pipeline (T3+T4): counted
//     s_waitcnt vmcnt(2) + raw s_barrier (never drain to 0 in-loop), tile j+2
//     staged into the freed buffer after the post-compute barrier.  LDS
//     50 KB (2x8K Ks + 2x8K Vs + 18K Ps) -> still 2 blocks/CU.  blockIdx.y
//     remap pairs J=(15-t) with J=t per CU -> every CU pair = 17 tiles
//     (was 24 worst / 17 avg).  Masking via per-wave chunk limit
//     lim = 8J + wave - 4*j2 (even-rounded ntc, NEG_INF pad = zero P).
//     prep / gemm128 / gemm_out frozen at R12 (180.5 us).
//     launch_bounds min-waves MUST stay 4 (6 spilled twice: R6, R7).
// Workspace (u16 elements, 1M = 2^20), 40 MB:
//   [0,4M)   Xbf [4096][1024] bf16      (Ab aliases this after QKV)
//   [4M,7M)  Wqkv^T (3 x [1024][1024])
//   [7M,11M) Q   [11M,15M) K   [15M,19M) V^T [32][64][2048]
//   [19M,20M) Wo^T
// ---------------------------------------------------------------------------

typedef unsigned short u16;
typedef __bf16 bf16x8 __attribute__((ext_vector_type(8)));
typedef float f32x4 __attribute__((ext_vector_type(4)));

#define TS 72               // padded LDS stride (transpose)
#define PS2 72              // P-tile LDS stride (64 cols + 8 pad -> +4 banks/row)
#define NEG_INF (-1e30f)
#define SC_LOG2 0.1803368801f   // log2(e)/8  (exp2-domain softmax scale)

#if __has_builtin(__builtin_amdgcn_exp2f)
#define EXP2(x) __builtin_amdgcn_exp2f(x)
#else
#define EXP2(x) exp2f(x)
#endif

#define GLD_LDS16(gp, lp) __builtin_amdgcn_global_load_lds( \
    (const __attribute__((address_space(1))) void*)(gp),    \
    (__attribute__((address_space(3))) void*)(lp), 16, 0, 0)

#define WAITV2() asm volatile("s_waitcnt vmcnt(2)" ::: "memory")
#define WAITV0() asm volatile("s_waitcnt vmcnt(0)" ::: "memory")
#define SBAR()   __builtin_amdgcn_s_barrier()
#define SCHED0() __builtin_amdgcn_sched_barrier(0)

__device__ __forceinline__ bf16x8 as_bf16x8(int4 v) { return __builtin_bit_cast(bf16x8, v); }
__device__ __forceinline__ u16 bf16_bits(float f) { return __builtin_bit_cast(u16, (__bf16)f); }

// Runtime dtype detect: f32-as-u16 low words have big exponent fields.
__device__ __forceinline__ bool detect_f32(const void* X) {
    const u16* x16 = (const u16*)X;
    int lane = threadIdx.x & 63;
    int hits = 0;
#pragma unroll
    for (int i = 0; i < 4; ++i) {
        u16 v = x16[lane * 4 + i];
        hits += (((v >> 7) & 0xFF) > 130) ? 1 : 0;
    }
    return __popcll(__ballot(hits > 0)) >= 8;
}

__device__ __forceinline__ bf16x8 load8(const void* p, size_t eoff, bool f32m) {
    if (!f32m) return as_bf16x8(*(const int4*)((const u16*)p + eoff));
    const float* f = (const float*)p + eoff;
    float4 a = *(const float4*)f;
    float4 b = *(const float4*)(f + 4);
    bf16x8 r;
    r[0] = (__bf16)a.x; r[1] = (__bf16)a.y; r[2] = (__bf16)a.z; r[3] = (__bf16)a.w;
    r[4] = (__bf16)b.x; r[5] = (__bf16)b.y; r[6] = (__bf16)b.z; r[7] = (__bf16)b.w;
    return r;
}

// ---------------- prep: 4 weight transposes (z=0..3) + X cvt (z=4) ----------
__global__ __launch_bounds__(256) void prep_all(const void* __restrict__ Wq,
                                                const void* __restrict__ Wk,
                                                const void* __restrict__ Wv,
                                                const void* __restrict__ Wo,
                                                const void* __restrict__ X,
                                                u16* __restrict__ Wt3,
                                                u16* __restrict__ Wot,
                                                u16* __restrict__ Xbf) {
    bool f32m = detect_f32(X);
    int z = blockIdx.z;
    if (z == 4) {
        int blk = blockIdx.y * 16 + blockIdx.x;
        size_t base = (size_t)blk * 16384 + threadIdx.x * 8;
#pragma unroll
        for (int i = 0; i < 8; ++i) {
            size_t eoff = base + (size_t)i * 2048;
            bf16x8 v = load8(X, eoff, f32m);
            *(int4*)(Xbf + eoff) = __builtin_bit_cast(int4, v);
        }
        return;
    }
    const void* in = (z == 0) ? Wq : (z == 1) ? Wk : (z == 2) ? Wv : Wo;
    u16* out = (z < 3) ? (Wt3 + (size_t)z * (1u << 20)) : Wot;
    __shared__ alignas(16) u16 T[64][TS];
    int r0 = blockIdx.y * 64, c0 = blockIdx.x * 64;
    int tr = threadIdx.x >> 3, tc8 = threadIdx.x & 7;
    bf16x8 v0 = load8(in, (size_t)(r0 + tr) * 1024 + c0 + tc8 * 8, f32m);
    bf16x8 v1 = load8(in, (size_t)(r0 + tr + 32) * 1024 + c0 + tc8 * 8, f32m);
    *(int4*)&T[tr][tc8 * 8]      = __builtin_bit_cast(int4, v0);
    *(int4*)&T[tr + 32][tc8 * 8] = __builtin_bit_cast(int4, v1);
    __syncthreads();
    for (int half = 0; half < 2; ++half) {
        int cr = tr + half * 32;
        u16 tmp[8];
#pragma unroll
        for (int i = 0; i < 8; ++i) tmp[i] = T[tc8 * 8 + i][cr];
        *(int4*)(out + (size_t)(c0 + cr) * 1024 + r0 + tc8 * 8) = *(int4*)tmp;
    }
}

// ---------------- 128x128-tile bf16 MFMA GEMM (QKV), XOR-swizzled LDS -------
// A: Xbf [4096][1024] bf16; Bt: Wqkv^T [3072][1024] bf16.  Pure GLD staging.
// 4 waves, each 64x64 subtile: 32 MFMA : 16 b128-reads per wave-iter.
__global__ __launch_bounds__(256, 4) void gemm128(const u16* __restrict__ A,
                                                  const u16* __restrict__ Bt,
                                                  u16* __restrict__ Cq, u16* __restrict__ Ck,
                                                  u16* __restrict__ Cv) {
    __shared__ alignas(16) u16 As[128 * 64];
    __shared__ alignas(16) u16 Bs[128 * 64];
    const int K = 1024;
    int tid = threadIdx.x, wave = tid >> 6, lane = tid & 63;
    int quad = lane >> 4, l16 = lane & 15;
    int wrow = wave >> 1, wcol = wave & 1;
    int m0 = blockIdx.x * 128, n0 = blockIdx.y * 128;
    int rlane = lane >> 3, kc = lane & 7;
    int scol = (kc ^ rlane) * 8;          // swizzled source column (u16)

    f32x4 acc[4][4] = {};

    for (int k0 = 0; k0 < K; k0 += 64) {
        __syncthreads();
#pragma unroll
        for (int i = 0; i < 4; ++i) {
            int rc = wave * 4 + i;       // 16 chunks of 8 rows each
            GLD_LDS16(A  + (size_t)(m0 + rc * 8 + rlane) * K + k0 + scol, As + rc * 512);
            GLD_LDS16(Bt + (size_t)(n0 + rc * 8 + rlane) * K + k0 + scol, Bs + rc * 512);
        }
        __syncthreads();
#pragma unroll
        for (int ks = 0; ks < 2; ++ks) {
            bf16x8 af[4], bfr[4];
#pragma unroll
            for (int i = 0; i < 4; ++i) {
                int row = wrow * 64 + i * 16 + l16;
                af[i] = as_bf16x8(*(const int4*)(As + row * 64 + (((ks * 4 + quad) ^ (row & 7)) * 8)));
            }
#pragma unroll
            for (int j = 0; j < 4; ++j) {
                int row = wcol * 64 + j * 16 + l16;
                bfr[j] = as_bf16x8(*(const int4*)(Bs + row * 64 + (((ks * 4 + quad) ^ (row & 7)) * 8)));
            }
#pragma unroll
            for (int i = 0; i < 4; ++i)
#pragma unroll
                for (int j = 0; j < 4; ++j)
                    acc[i][j] = __builtin_amdgcn_mfma_f32_16x16x32_bf16(af[i], bfr[j], acc[i][j], 0, 0, 0);
        }
    }

#pragma unroll
    for (int i = 0; i < 4; ++i)
#pragma unroll
        for (int j = 0; j < 4; ++j)
#pragma unroll
            for (int r = 0; r < 4; ++r) {
                int m = m0 + wrow * 64 + i * 16 + quad * 4 + r;
                int n = n0 + wcol * 64 + j * 16 + l16;
                float f = acc[i][j][r];
                if (n < 1024)       Cq[(size_t)m * 1024 + n] = bf16_bits(f);
                else if (n < 2048)  Ck[(size_t)m * 1024 + n - 1024] = bf16_bits(f);
                else {
                    int n2 = n - 2048;
                    int bh = ((m >> 11) << 4) | (n2 >> 6), d = n2 & 63, t = m & 2047;
                    Cv[(((size_t)bh * 64 + d) << 11) + t] = bf16_bits(f);
                }
            }
}

// ---------------- 64x128-tile GEMM (out-proj), R11-exact --------------------
__global__ __launch_bounds__(256, 4) void gemm_out(const u16* __restrict__ A,
                                                   const u16* __restrict__ Bt,
                                                   void* __restrict__ Cout,
                                                   const void* __restrict__ Xdet) {
    bool f32m = detect_f32(Xdet);
    __shared__ alignas(16) u16 As[64 * 64];
    __shared__ alignas(16) u16 Bs[128 * 64];
    const int K = 1024;
    int tid = threadIdx.x, wave = tid >> 6, lane = tid & 63;
    int quad = lane >> 4, l16 = lane & 15;
    int wrow = wave & 1, wcol = wave >> 1;
    int m0 = blockIdx.x * 64, n0 = blockIdx.y * 128;
    int rlane = lane >> 3, kc = lane & 7;
    int scol = (kc ^ rlane) * 8;

    f32x4 acc[2][4] = {};

    for (int k0 = 0; k0 < K; k0 += 64) {
        __syncthreads();
#pragma unroll
        for (int i = 0; i < 4; ++i) {
            int rc = wave * 4 + i;
            GLD_LDS16(Bt + (size_t)(n0 + rc * 8 + rlane) * K + k0 + scol, Bs + rc * 512);
        }
#pragma unroll
        for (int i = 0; i < 2; ++i) {
            int rc = wave * 2 + i;
            GLD_LDS16(A + (size_t)(m0 + rc * 8 + rlane) * K + k0 + scol, As + rc * 512);
        }
        __syncthreads();
#pragma unroll
        for (int ks = 0; ks < 2; ++ks) {
            bf16x8 af[2], bfr[4];
#pragma unroll
            for (int i = 0; i < 2; ++i) {
                int row = wrow * 32 + i * 16 + l16;
                af[i] = as_bf16x8(*(const int4*)(As + row * 64 + (((ks * 4 + quad) ^ (row & 7)) * 8)));
            }
#pragma unroll
            for (int j = 0; j < 4; ++j) {
                int row = wcol * 64 + j * 16 + l16;
                bfr[j] = as_bf16x8(*(const int4*)(Bs + row * 64 + (((ks * 4 + quad) ^ (row & 7)) * 8)));
            }
#pragma unroll
            for (int i = 0; i < 2; ++i)
#pragma unroll
                for (int j = 0; j < 4; ++j)
                    acc[i][j] = __builtin_amdgcn_mfma_f32_16x16x32_bf16(af[i], bfr[j], acc[i][j], 0, 0, 0);
        }
    }

#pragma unroll
    for (int i = 0; i < 2; ++i)
#pragma unroll
        for (int j = 0; j < 4; ++j)
#pragma unroll
            for (int r = 0; r < 4; ++r) {
                int m = m0 + wrow * 32 + i * 16 + quad * 4 + r;
                int n = n0 + wcol * 64 + j * 16 + l16;
                float f = acc[i][j][r];
                if (f32m) ((float*)Cout)[(size_t)m * 1024 + n] = f;
                else      ((u16*)Cout)[(size_t)m * 1024 + n] = bf16_bits(f);
            }
}

// ---------------- flash attention (R13: dbuf KVBLK=64, counted vmcnt) -------
// Per tile per wave: 1 K-GLD + 1 V-GLD.  Steady state: next tile's 2 loads
// stay in flight across both raw barriers (WAITV2); drain-to-0 only at the
// final tile.  Ps rows are wave-exclusive (no cross-wave barrier needed).
__global__ __launch_bounds__(512, 4) void attn_kernel(const u16* __restrict__ Qb,
                                                      const u16* __restrict__ Kb,
                                                      const u16* __restrict__ Vt,
                                                      u16* __restrict__ Ab) {
    __shared__ alignas(16) u16 Ks[2][64 * 64];   // swizzled [kv][d], double-buffered
    __shared__ alignas(16) u16 Vs[2][64 * 64];   // swizzled [d][t], double-buffered
    __shared__ alignas(16) u16 Ps[128 * PS2];    // [q 128][kv 64] padded

    int tid = threadIdx.x, wave = tid >> 6, lane = tid & 63;
    int quad = lane >> 4, l16 = lane & 15;
    int bh = blockIdx.x;                 // x fastest => heavy-J blocks first
    // Complementary pairing: first 256 blocks J=15..8, next 256 J=0..7 ->
    // each CU's resident pair sums to exactly 17 q-tiles of work.
    int J = (blockIdx.y < 8) ? (15 - (int)blockIdx.y) : ((int)blockIdx.y - 8);
    int b = bh >> 4, h = bh & 15;
    int q0 = J * 128;
    int r8 = lane >> 3, kc = lane & 7;
    int srow = wave * 8 + r8;            // staging row within 64-tile
    int sch = kc ^ (srow & 7);           // swizzled source chunk

    const u16* qrow = Qb + (size_t)(b * 2048 + q0 + wave * 16 + l16) * 1024 + h * 64;
    bf16x8 qa0 = as_bf16x8(*(const int4*)(qrow + quad * 8));
    bf16x8 qa1 = as_bf16x8(*(const int4*)(qrow + 32 + quad * 8));

    f32x4 o[4] = {};
    float lrow[4] = {0.0f, 0.0f, 0.0f, 0.0f};

    const u16* kbase = Kb + (size_t)(b * 2048) * 1024 + h * 64;
    const u16* vbase = Vt + (size_t)bh * 64 * 2048;
    const u16* ksrc = kbase + (size_t)srow * 1024 + sch * 8;   // + t0*1024 per tile
    const u16* vsrc = vbase + (size_t)srow * 2048 + sch * 8;   // + t0 per tile

    const int NT = 2 * J + 2;            // 64-wide kv tiles

    // prologue: stage tiles 0 and 1 (issue order defines vmcnt accounting)
    GLD_LDS16(ksrc, &Ks[0][wave * 512]);
    GLD_LDS16(vsrc, &Vs[0][wave * 512]);
    GLD_LDS16(ksrc + (size_t)64 * 1024, &Ks[1][wave * 512]);
    GLD_LDS16(vsrc + 64, &Vs[1][wave * 512]);

    for (int j2 = 0; j2 < NT; ++j2) {
        int cur = j2 & 1;
        const u16* KsC = Ks[cur];
        const u16* VsC = Vs[cur];
        if (j2 + 1 < NT) { WAITV2(); } else { WAITV0(); }
        SCHED0();
        SBAR();                          // tile j2's K/V visible to all waves
        SCHED0();

        // causal chunk limit: kv chunk (4*j2+nt) vs q chunk (8J+wave)
        int lim = 8 * J + wave - 4 * j2;           // nt<lim full, ==lim partial
        int ntc = (lim >= 3) ? 4 : ((lim < 0) ? 0 : ((lim + 2) & ~1));

        f32x4 s[4];
#pragma unroll
        for (int nt = 0; nt < 4; ++nt) {
            if (nt >= ntc) continue;
            if (nt > lim) {
                s[nt][0] = NEG_INF; s[nt][1] = NEG_INF; s[nt][2] = NEG_INF; s[nt][3] = NEG_INF;
                continue;
            }
            int row = nt * 16 + l16;
            int sw = row & 7;
            f32x4 a = {};
            bf16x8 b0 = as_bf16x8(*(const int4*)(KsC + row * 64 + ((quad ^ sw) * 8)));
            a = __builtin_amdgcn_mfma_f32_16x16x32_bf16(qa0, b0, a, 0, 0, 0);
            bf16x8 b1 = as_bf16x8(*(const int4*)(KsC + row * 64 + (((4 + quad) ^ sw) * 8)));
            a = __builtin_amdgcn_mfma_f32_16x16x32_bf16(qa1, b1, a, 0, 0, 0);
            a = a * SC_LOG2;
            if (nt == lim) {
#pragma unroll
                for (int r = 0; r < 4; ++r)
                    if (l16 > quad * 4 + r) a[r] = NEG_INF;
            }
            s[nt] = a;
        }

#pragma unroll
        for (int r = 0; r < 4; ++r) {
            float psum = 0.0f;
            int prow = (wave * 16 + quad * 4 + r) * PS2;
#pragma unroll
            for (int nt = 0; nt < 4; ++nt) {
                if (nt >= ntc) continue;
                float p = EXP2(s[nt][r]);
                psum += p;
                Ps[prow + nt * 16 + l16] = bf16_bits(p);
            }
            psum += __shfl_xor(psum, 1, 16);
            psum += __shfl_xor(psum, 2, 16);
            psum += __shfl_xor(psum, 4, 16);
            psum += __shfl_xor(psum, 8, 16);
            lrow[r] += psum;
        }

        int ksm = ntc >> 1;
#pragma unroll
        for (int ks = 0; ks < 2; ++ks) {
            if (ks >= ksm) continue;
            bf16x8 pa = as_bf16x8(*(const int4*)(Ps + (wave * 16 + l16) * PS2 + ks * 32 + quad * 8));
#pragma unroll
            for (int d4 = 0; d4 < 4; ++d4) {
                int vrow = d4 * 16 + l16;
                bf16x8 vb = as_bf16x8(*(const int4*)(VsC + vrow * 64 + (((ks * 4 + quad) ^ (vrow & 7)) * 8)));
                o[d4] = __builtin_amdgcn_mfma_f32_16x16x32_bf16(pa, vb, o[d4], 0, 0, 0);
            }
        }

        SCHED0();
        SBAR();                          // all waves done reading buf[cur]
        SCHED0();
        if (j2 + 2 < NT) {               // prefetch tile j2+2 into freed buffer
            int t0n = (j2 + 2) * 64;
            GLD_LDS16(ksrc + (size_t)t0n * 1024, &Ks[cur][wave * 512]);
            GLD_LDS16(vsrc + t0n, &Vs[cur][wave * 512]);
        }
    }

    u16* arow = Ab + (size_t)(b * 2048 + q0 + wave * 16) * 1024 + h * 64;
#pragma unroll
    for (int r = 0; r < 4; ++r) {
        float inv = 1.0f / lrow[r];
#pragma unroll
        for (int d4 = 0; d4 < 4; ++d4)
            arow[(quad * 4 + r) * 1024 + d4 * 16 + l16] = bf16_bits(o[d4][r] * inv);
    }
}

// ---------------------------------------------------------------------------
extern "C" void kernel_launch(void* const* d_in, const int* in_sizes, int n_in,
                              void* d_out, int out_size, void* d_ws, size_t ws_size,
                              hipStream_t stream) {
    (void)in_sizes; (void)n_in; (void)out_size; (void)ws_size;
    const void* X  = d_in[0];
    const void* Wq = d_in[1];
    const void* Wk = d_in[2];
    const void* Wv = d_in[3];
    const void* Wo = d_in[4];
    u16* ws16 = (u16*)d_ws;
    const size_t M1 = 1u << 20;
    u16* Xbf = ws16 + 0 * M1;        // [0,4M)
    u16* Wt3 = ws16 + 4 * M1;        // [4M,7M)
    u16* Qb  = ws16 + 7 * M1;
    u16* Kb  = ws16 + 11 * M1;
    u16* Vt  = ws16 + 15 * M1;
    u16* Wot = ws16 + 19 * M1;
    u16* Ab  = ws16 + 0 * M1;        // aliases Xbf (dead after QKV GEMM)

    prep_all<<<dim3(16, 16, 5), 256, 0, stream>>>(Wq, Wk, Wv, Wo, X, Wt3, Wot, Xbf);
    gemm128<<<dim3(32, 24), 256, 0, stream>>>(Xbf, Wt3, Qb, Kb, Vt);
    attn_kernel<<<dim3(32, 16), 512, 0, stream>>>(Qb, Kb, Vt, Ab);
    gemm_out<<<dim3(64, 8), 256, 0, stream>>>(Ab, Wot, d_out, X);
}

// Round 2
// 178.565 us; speedup vs baseline: 1.1314x; 1.1314x over previous
//
#include <hip/hip_runtime.h>
#include <hip/hip_bf16.h>

// ---------------------------------------------------------------------------
// Causal MHA forward.  B=2, T=2048, H=16, Dk=64, D=1024.  Inputs float32;
// internal pipeline bf16 MFMA.
// R14: attn REVERTED to R12 structure (KVBLK=128, single-buffer, 54 us) --
//     R13's KVBLK=64 dbuf pipeline regressed to 75 us (2x barriers + 2x
//     shfl-reduce chains per kv; loads were never the bottleneck).  Kept
//     from R13: complementary-J blockIdx.y remap (verified correct) --
//     resident CU pairs (i, i+256) now sum to exactly 17 kv-iters
//     (was 24 worst / 17 mean with plain LPT).
//     prep / gemm128 / gemm_out frozen at R12 (180.5 us).
//     launch_bounds min-waves MUST stay 4 (6 spilled twice: R6, R7).
// Workspace (u16 elements, 1M = 2^20), 40 MB:
//   [0,4M)   Xbf [4096][1024] bf16      (Ab aliases this after QKV)
//   [4M,7M)  Wqkv^T (3 x [1024][1024])
//   [7M,11M) Q   [11M,15M) K   [15M,19M) V^T [32][64][2048]
//   [19M,20M) Wo^T
// ---------------------------------------------------------------------------

typedef unsigned short u16;
typedef __bf16 bf16x8 __attribute__((ext_vector_type(8)));
typedef float f32x4 __attribute__((ext_vector_type(4)));

#define TS 72               // padded LDS stride (transpose)
#define PS 136              // P-tile LDS stride (R5-proven)
#define NEG_INF (-1e30f)
#define SC_LOG2 0.1803368801f   // log2(e)/8  (exp2-domain softmax scale)

#if __has_builtin(__builtin_amdgcn_exp2f)
#define EXP2(x) __builtin_amdgcn_exp2f(x)
#else
#define EXP2(x) exp2f(x)
#endif

#define GLD_LDS16(gp, lp) __builtin_amdgcn_global_load_lds( \
    (const __attribute__((address_space(1))) void*)(gp),    \
    (__attribute__((address_space(3))) void*)(lp), 16, 0, 0)

__device__ __forceinline__ bf16x8 as_bf16x8(int4 v) { return __builtin_bit_cast(bf16x8, v); }
__device__ __forceinline__ u16 bf16_bits(float f) { return __builtin_bit_cast(u16, (__bf16)f); }

// Runtime dtype detect: f32-as-u16 low words have big exponent fields.
__device__ __forceinline__ bool detect_f32(const void* X) {
    const u16* x16 = (const u16*)X;
    int lane = threadIdx.x & 63;
    int hits = 0;
#pragma unroll
    for (int i = 0; i < 4; ++i) {
        u16 v = x16[lane * 4 + i];
        hits += (((v >> 7) & 0xFF) > 130) ? 1 : 0;
    }
    return __popcll(__ballot(hits > 0)) >= 8;
}

__device__ __forceinline__ bf16x8 load8(const void* p, size_t eoff, bool f32m) {
    if (!f32m) return as_bf16x8(*(const int4*)((const u16*)p + eoff));
    const float* f = (const float*)p + eoff;
    float4 a = *(const float4*)f;
    float4 b = *(const float4*)(f + 4);
    bf16x8 r;
    r[0] = (__bf16)a.x; r[1] = (__bf16)a.y; r[2] = (__bf16)a.z; r[3] = (__bf16)a.w;
    r[4] = (__bf16)b.x; r[5] = (__bf16)b.y; r[6] = (__bf16)b.z; r[7] = (__bf16)b.w;
    return r;
}

// ---------------- prep: 4 weight transposes (z=0..3) + X cvt (z=4) ----------
__global__ __launch_bounds__(256) void prep_all(const void* __restrict__ Wq,
                                                const void* __restrict__ Wk,
                                                const void* __restrict__ Wv,
                                                const void* __restrict__ Wo,
                                                const void* __restrict__ X,
                                                u16* __restrict__ Wt3,
                                                u16* __restrict__ Wot,
                                                u16* __restrict__ Xbf) {
    bool f32m = detect_f32(X);
    int z = blockIdx.z;
    if (z == 4) {
        int blk = blockIdx.y * 16 + blockIdx.x;
        size_t base = (size_t)blk * 16384 + threadIdx.x * 8;
#pragma unroll
        for (int i = 0; i < 8; ++i) {
            size_t eoff = base + (size_t)i * 2048;
            bf16x8 v = load8(X, eoff, f32m);
            *(int4*)(Xbf + eoff) = __builtin_bit_cast(int4, v);
        }
        return;
    }
    const void* in = (z == 0) ? Wq : (z == 1) ? Wk : (z == 2) ? Wv : Wo;
    u16* out = (z < 3) ? (Wt3 + (size_t)z * (1u << 20)) : Wot;
    __shared__ alignas(16) u16 T[64][TS];
    int r0 = blockIdx.y * 64, c0 = blockIdx.x * 64;
    int tr = threadIdx.x >> 3, tc8 = threadIdx.x & 7;
    bf16x8 v0 = load8(in, (size_t)(r0 + tr) * 1024 + c0 + tc8 * 8, f32m);
    bf16x8 v1 = load8(in, (size_t)(r0 + tr + 32) * 1024 + c0 + tc8 * 8, f32m);
    *(int4*)&T[tr][tc8 * 8]      = __builtin_bit_cast(int4, v0);
    *(int4*)&T[tr + 32][tc8 * 8] = __builtin_bit_cast(int4, v1);
    __syncthreads();
    for (int half = 0; half < 2; ++half) {
        int cr = tr + half * 32;
        u16 tmp[8];
#pragma unroll
        for (int i = 0; i < 8; ++i) tmp[i] = T[tc8 * 8 + i][cr];
        *(int4*)(out + (size_t)(c0 + cr) * 1024 + r0 + tc8 * 8) = *(int4*)tmp;
    }
}

// ---------------- 128x128-tile bf16 MFMA GEMM (QKV), XOR-swizzled LDS -------
// A: Xbf [4096][1024] bf16; Bt: Wqkv^T [3072][1024] bf16.  Pure GLD staging.
// 4 waves, each 64x64 subtile: 32 MFMA : 16 b128-reads per wave-iter.
__global__ __launch_bounds__(256, 4) void gemm128(const u16* __restrict__ A,
                                                  const u16* __restrict__ Bt,
                                                  u16* __restrict__ Cq, u16* __restrict__ Ck,
                                                  u16* __restrict__ Cv) {
    __shared__ alignas(16) u16 As[128 * 64];
    __shared__ alignas(16) u16 Bs[128 * 64];
    const int K = 1024;
    int tid = threadIdx.x, wave = tid >> 6, lane = tid & 63;
    int quad = lane >> 4, l16 = lane & 15;
    int wrow = wave >> 1, wcol = wave & 1;
    int m0 = blockIdx.x * 128, n0 = blockIdx.y * 128;
    int rlane = lane >> 3, kc = lane & 7;
    int scol = (kc ^ rlane) * 8;          // swizzled source column (u16)

    f32x4 acc[4][4] = {};

    for (int k0 = 0; k0 < K; k0 += 64) {
        __syncthreads();
#pragma unroll
        for (int i = 0; i < 4; ++i) {
            int rc = wave * 4 + i;       // 16 chunks of 8 rows each
            GLD_LDS16(A  + (size_t)(m0 + rc * 8 + rlane) * K + k0 + scol, As + rc * 512);
            GLD_LDS16(Bt + (size_t)(n0 + rc * 8 + rlane) * K + k0 + scol, Bs + rc * 512);
        }
        __syncthreads();
#pragma unroll
        for (int ks = 0; ks < 2; ++ks) {
            bf16x8 af[4], bfr[4];
#pragma unroll
            for (int i = 0; i < 4; ++i) {
                int row = wrow * 64 + i * 16 + l16;
                af[i] = as_bf16x8(*(const int4*)(As + row * 64 + (((ks * 4 + quad) ^ (row & 7)) * 8)));
            }
#pragma unroll
            for (int j = 0; j < 4; ++j) {
                int row = wcol * 64 + j * 16 + l16;
                bfr[j] = as_bf16x8(*(const int4*)(Bs + row * 64 + (((ks * 4 + quad) ^ (row & 7)) * 8)));
            }
#pragma unroll
            for (int i = 0; i < 4; ++i)
#pragma unroll
                for (int j = 0; j < 4; ++j)
                    acc[i][j] = __builtin_amdgcn_mfma_f32_16x16x32_bf16(af[i], bfr[j], acc[i][j], 0, 0, 0);
        }
    }

#pragma unroll
    for (int i = 0; i < 4; ++i)
#pragma unroll
        for (int j = 0; j < 4; ++j)
#pragma unroll
            for (int r = 0; r < 4; ++r) {
                int m = m0 + wrow * 64 + i * 16 + quad * 4 + r;
                int n = n0 + wcol * 64 + j * 16 + l16;
                float f = acc[i][j][r];
                if (n < 1024)       Cq[(size_t)m * 1024 + n] = bf16_bits(f);
                else if (n < 2048)  Ck[(size_t)m * 1024 + n - 1024] = bf16_bits(f);
                else {
                    int n2 = n - 2048;
                    int bh = ((m >> 11) << 4) | (n2 >> 6), d = n2 & 63, t = m & 2047;
                    Cv[(((size_t)bh * 64 + d) << 11) + t] = bf16_bits(f);
                }
            }
}

// ---------------- 64x128-tile GEMM (out-proj), R11-exact --------------------
__global__ __launch_bounds__(256, 4) void gemm_out(const u16* __restrict__ A,
                                                   const u16* __restrict__ Bt,
                                                   void* __restrict__ Cout,
                                                   const void* __restrict__ Xdet) {
    bool f32m = detect_f32(Xdet);
    __shared__ alignas(16) u16 As[64 * 64];
    __shared__ alignas(16) u16 Bs[128 * 64];
    const int K = 1024;
    int tid = threadIdx.x, wave = tid >> 6, lane = tid & 63;
    int quad = lane >> 4, l16 = lane & 15;
    int wrow = wave & 1, wcol = wave >> 1;
    int m0 = blockIdx.x * 64, n0 = blockIdx.y * 128;
    int rlane = lane >> 3, kc = lane & 7;
    int scol = (kc ^ rlane) * 8;

    f32x4 acc[2][4] = {};

    for (int k0 = 0; k0 < K; k0 += 64) {
        __syncthreads();
#pragma unroll
        for (int i = 0; i < 4; ++i) {
            int rc = wave * 4 + i;
            GLD_LDS16(Bt + (size_t)(n0 + rc * 8 + rlane) * K + k0 + scol, Bs + rc * 512);
        }
#pragma unroll
        for (int i = 0; i < 2; ++i) {
            int rc = wave * 2 + i;
            GLD_LDS16(A + (size_t)(m0 + rc * 8 + rlane) * K + k0 + scol, As + rc * 512);
        }
        __syncthreads();
#pragma unroll
        for (int ks = 0; ks < 2; ++ks) {
            bf16x8 af[2], bfr[4];
#pragma unroll
            for (int i = 0; i < 2; ++i) {
                int row = wrow * 32 + i * 16 + l16;
                af[i] = as_bf16x8(*(const int4*)(As + row * 64 + (((ks * 4 + quad) ^ (row & 7)) * 8)));
            }
#pragma unroll
            for (int j = 0; j < 4; ++j) {
                int row = wcol * 64 + j * 16 + l16;
                bfr[j] = as_bf16x8(*(const int4*)(Bs + row * 64 + (((ks * 4 + quad) ^ (row & 7)) * 8)));
            }
#pragma unroll
            for (int i = 0; i < 2; ++i)
#pragma unroll
                for (int j = 0; j < 4; ++j)
                    acc[i][j] = __builtin_amdgcn_mfma_f32_16x16x32_bf16(af[i], bfr[j], acc[i][j], 0, 0, 0);
        }
    }

#pragma unroll
    for (int i = 0; i < 2; ++i)
#pragma unroll
        for (int j = 0; j < 4; ++j)
#pragma unroll
            for (int r = 0; r < 4; ++r) {
                int m = m0 + wrow * 32 + i * 16 + quad * 4 + r;
                int n = n0 + wcol * 64 + j * 16 + l16;
                float f = acc[i][j][r];
                if (f32m) ((float*)Cout)[(size_t)m * 1024 + n] = f;
                else      ((u16*)Cout)[(size_t)m * 1024 + n] = bf16_bits(f);
            }
}

// ---------------- flash attention (R12-exact + complementary-J pairing) -----
__global__ __launch_bounds__(512, 4) void attn_kernel(const u16* __restrict__ Qb,
                                                      const u16* __restrict__ Kb,
                                                      const u16* __restrict__ Vt,
                                                      u16* __restrict__ Ab) {
    __shared__ alignas(16) u16 Ks[128 * 64];   // swizzled [kv][d]
    __shared__ alignas(16) u16 Vs[64 * 128];   // swizzled [d][t]
    __shared__ alignas(16) u16 Ps[128 * PS];   // [q 128][kv 128] padded

    int tid = threadIdx.x, wave = tid >> 6, lane = tid & 63;
    int quad = lane >> 4, l16 = lane & 15;
    int bh = blockIdx.x;                 // x fastest => heavy-J blocks first
    // Complementary pairing: first 256 blocks J=15..8, next 256 J=0..7 ->
    // resident CU pairs (i, i+256) sum to exactly 17 kv-iters (was 24 worst).
    int J = (blockIdx.y < 8) ? (15 - (int)blockIdx.y) : ((int)blockIdx.y - 8);
    int b = bh >> 4, h = bh & 15;
    int q0 = J * 128;
    int kr4 = lane >> 3, kc = lane & 7;   // K staging: 8 rows x 8 chunks
    int vr4 = lane >> 4, vc = lane & 15;  // V staging: 4 rows x 16 chunks

    const u16* qrow = Qb + (size_t)(b * 2048 + q0 + wave * 16 + l16) * 1024 + h * 64;
    bf16x8 qa0 = as_bf16x8(*(const int4*)(qrow + quad * 8));
    bf16x8 qa1 = as_bf16x8(*(const int4*)(qrow + 32 + quad * 8));

    f32x4 o[4] = {};
    float lrow[4] = {0.0f, 0.0f, 0.0f, 0.0f};

    const u16* kbase = Kb + (size_t)(b * 2048) * 1024 + h * 64;
    const u16* vbase = Vt + (size_t)bh * 64 * 2048;

    for (int j2 = 0; j2 <= J; ++j2) {
        int t0 = j2 * 128;
        __syncthreads();
#pragma unroll
        for (int i = 0; i < 2; ++i) {
            int rb = (wave * 2 + i) * 8;
            int grow = rb + kr4;
            int gch = kc ^ (grow & 7);
            GLD_LDS16(kbase + (size_t)(t0 + grow) * 1024 + gch * 8, Ks + rb * 64);
        }
#pragma unroll
        for (int i = 0; i < 2; ++i) {
            int rb = (wave * 2 + i) * 4;
            int grow = rb + vr4;
            int gch = vc ^ (grow & 15);
            GLD_LDS16(vbase + (size_t)grow * 2048 + t0 + gch * 8, Vs + rb * 128);
        }
        __syncthreads();

        bool diag = (j2 == J);
        int ntc = diag ? ((wave & ~1) + 2) : 8;

        f32x4 s[8];
#pragma unroll
        for (int nt = 0; nt < 8; ++nt) {
            if (nt >= ntc) continue;
            if (diag && nt > wave) {
                s[nt][0] = NEG_INF; s[nt][1] = NEG_INF; s[nt][2] = NEG_INF; s[nt][3] = NEG_INF;
                continue;
            }
            int row = nt * 16 + l16;
            int sw = row & 7;
            f32x4 a = {};
            bf16x8 b0 = as_bf16x8(*(const int4*)(Ks + row * 64 + ((quad ^ sw) * 8)));
            a = __builtin_amdgcn_mfma_f32_16x16x32_bf16(qa0, b0, a, 0, 0, 0);
            bf16x8 b1 = as_bf16x8(*(const int4*)(Ks + row * 64 + (((4 + quad) ^ sw) * 8)));
            a = __builtin_amdgcn_mfma_f32_16x16x32_bf16(qa1, b1, a, 0, 0, 0);
            a = a * SC_LOG2;
            if (diag && nt == wave) {
#pragma unroll
                for (int r = 0; r < 4; ++r)
                    if (l16 > quad * 4 + r) a[r] = NEG_INF;
            }
            s[nt] = a;
        }

#pragma unroll
        for (int r = 0; r < 4; ++r) {
            float psum = 0.0f;
            int prow = (wave * 16 + quad * 4 + r) * PS;
#pragma unroll
            for (int nt = 0; nt < 8; ++nt) {
                if (nt >= ntc) continue;
                float p = EXP2(s[nt][r]);
                psum += p;
                Ps[prow + nt * 16 + l16] = bf16_bits(p);
            }
            psum += __shfl_xor(psum, 1, 16);
            psum += __shfl_xor(psum, 2, 16);
            psum += __shfl_xor(psum, 4, 16);
            psum += __shfl_xor(psum, 8, 16);
            lrow[r] += psum;
        }

        int ksm = ntc >> 1;
#pragma unroll
        for (int ks = 0; ks < 4; ++ks) {
            if (ks >= ksm) continue;
            bf16x8 pa = as_bf16x8(*(const int4*)(Ps + (wave * 16 + l16) * PS + ks * 32 + quad * 8));
#pragma unroll
            for (int d4 = 0; d4 < 4; ++d4) {
                int vrow = d4 * 16 + l16;
                bf16x8 vb = as_bf16x8(*(const int4*)(Vs + vrow * 128 + (((ks * 4 + quad) ^ l16) * 8)));
                o[d4] = __builtin_amdgcn_mfma_f32_16x16x32_bf16(pa, vb, o[d4], 0, 0, 0);
            }
        }
    }

    u16* arow = Ab + (size_t)(b * 2048 + q0 + wave * 16) * 1024 + h * 64;
#pragma unroll
    for (int r = 0; r < 4; ++r) {
        float inv = 1.0f / lrow[r];
#pragma unroll
        for (int d4 = 0; d4 < 4; ++d4)
            arow[(quad * 4 + r) * 1024 + d4 * 16 + l16] = bf16_bits(o[d4][r] * inv);
    }
}

// ---------------------------------------------------------------------------
extern "C" void kernel_launch(void* const* d_in, const int* in_sizes, int n_in,
                              void* d_out, int out_size, void* d_ws, size_t ws_size,
                              hipStream_t stream) {
    (void)in_sizes; (void)n_in; (void)out_size; (void)ws_size;
    const void* X  = d_in[0];
    const void* Wq = d_in[1];
    const void* Wk = d_in[2];
    const void* Wv = d_in[3];
    const void* Wo = d_in[4];
    u16* ws16 = (u16*)d_ws;
    const size_t M1 = 1u << 20;
    u16* Xbf = ws16 + 0 * M1;        // [0,4M)
    u16* Wt3 = ws16 + 4 * M1;        // [4M,7M)
    u16* Qb  = ws16 + 7 * M1;
    u16* Kb  = ws16 + 11 * M1;
    u16* Vt  = ws16 + 15 * M1;
    u16* Wot = ws16 + 19 * M1;
    u16* Ab  = ws16 + 0 * M1;        // aliases Xbf (dead after QKV GEMM)

    prep_all<<<dim3(16, 16, 5), 256, 0, stream>>>(Wq, Wk, Wv, Wo, X, Wt3, Wot, Xbf);
    gemm128<<<dim3(32, 24), 256, 0, stream>>>(Xbf, Wt3, Qb, Kb, Vt);
    attn_kernel<<<dim3(32, 16), 512, 0, stream>>>(Qb, Kb, Vt, Ab);
    gemm_out<<<dim3(64, 8), 256, 0, stream>>>(Ab, Wot, d_out, X);
}

// Round 3
// 171.197 us; speedup vs baseline: 1.1800x; 1.0430x over previous
//
#include <hip/hip_runtime.h>
#include <hip/hip_bf16.h>

// ---------------------------------------------------------------------------
// Causal MHA forward.  B=2, T=2048, H=16, Dk=64, D=1024.  Inputs float32;
// internal pipeline bf16 MFMA.
// R15: attn QK^T SWAPPED (mfma(K,Q) -> S^T, q along l16, kv along quad*4+r).
//     Row-sum is now lane-local: the 16 shfl_xor per tile (272/block serial
//     ds_bpermute chain) collapse to 2 shfl_xor + 4 shfl at the epilogue.
//     P store vectorized to ds_write_b64 (8/tile vs 32).  PV + V layout +
//     epilogue unchanged (Ps read pattern is already the A-frag layout for
//     P[q=l16][kv]).  Diag mask flipped: quad*4+r > l16.
//     Kept from R14: complementary-J pairing (attn 54.0 -> 50.6 us).
//     prep / gemm128 / gemm_out frozen at R12.
//     launch_bounds min-waves MUST stay 4 (6 spilled twice: R6, R7).
// Workspace (u16 elements, 1M = 2^20), 40 MB:
//   [0,4M)   Xbf [4096][1024] bf16      (Ab aliases this after QKV)
//   [4M,7M)  Wqkv^T (3 x [1024][1024])
//   [7M,11M) Q   [11M,15M) K   [15M,19M) V^T [32][64][2048]
//   [19M,20M) Wo^T
// ---------------------------------------------------------------------------

typedef unsigned short u16;
typedef __bf16 bf16x8 __attribute__((ext_vector_type(8)));
typedef float f32x4 __attribute__((ext_vector_type(4)));
typedef u16 u16x4 __attribute__((ext_vector_type(4)));

#define TS 72               // padded LDS stride (transpose)
#define PS 136              // P-tile LDS stride (R5-proven)
#define NEG_INF (-1e30f)
#define SC_LOG2 0.1803368801f   // log2(e)/8  (exp2-domain softmax scale)

#if __has_builtin(__builtin_amdgcn_exp2f)
#define EXP2(x) __builtin_amdgcn_exp2f(x)
#else
#define EXP2(x) exp2f(x)
#endif

#define GLD_LDS16(gp, lp) __builtin_amdgcn_global_load_lds( \
    (const __attribute__((address_space(1))) void*)(gp),    \
    (__attribute__((address_space(3))) void*)(lp), 16, 0, 0)

__device__ __forceinline__ bf16x8 as_bf16x8(int4 v) { return __builtin_bit_cast(bf16x8, v); }
__device__ __forceinline__ u16 bf16_bits(float f) { return __builtin_bit_cast(u16, (__bf16)f); }

// Runtime dtype detect: f32-as-u16 low words have big exponent fields.
__device__ __forceinline__ bool detect_f32(const void* X) {
    const u16* x16 = (const u16*)X;
    int lane = threadIdx.x & 63;
    int hits = 0;
#pragma unroll
    for (int i = 0; i < 4; ++i) {
        u16 v = x16[lane * 4 + i];
        hits += (((v >> 7) & 0xFF) > 130) ? 1 : 0;
    }
    return __popcll(__ballot(hits > 0)) >= 8;
}

__device__ __forceinline__ bf16x8 load8(const void* p, size_t eoff, bool f32m) {
    if (!f32m) return as_bf16x8(*(const int4*)((const u16*)p + eoff));
    const float* f = (const float*)p + eoff;
    float4 a = *(const float4*)f;
    float4 b = *(const float4*)(f + 4);
    bf16x8 r;
    r[0] = (__bf16)a.x; r[1] = (__bf16)a.y; r[2] = (__bf16)a.z; r[3] = (__bf16)a.w;
    r[4] = (__bf16)b.x; r[5] = (__bf16)b.y; r[6] = (__bf16)b.z; r[7] = (__bf16)b.w;
    return r;
}

// ---------------- prep: 4 weight transposes (z=0..3) + X cvt (z=4) ----------
__global__ __launch_bounds__(256) void prep_all(const void* __restrict__ Wq,
                                                const void* __restrict__ Wk,
                                                const void* __restrict__ Wv,
                                                const void* __restrict__ Wo,
                                                const void* __restrict__ X,
                                                u16* __restrict__ Wt3,
                                                u16* __restrict__ Wot,
                                                u16* __restrict__ Xbf) {
    bool f32m = detect_f32(X);
    int z = blockIdx.z;
    if (z == 4) {
        int blk = blockIdx.y * 16 + blockIdx.x;
        size_t base = (size_t)blk * 16384 + threadIdx.x * 8;
#pragma unroll
        for (int i = 0; i < 8; ++i) {
            size_t eoff = base + (size_t)i * 2048;
            bf16x8 v = load8(X, eoff, f32m);
            *(int4*)(Xbf + eoff) = __builtin_bit_cast(int4, v);
        }
        return;
    }
    const void* in = (z == 0) ? Wq : (z == 1) ? Wk : (z == 2) ? Wv : Wo;
    u16* out = (z < 3) ? (Wt3 + (size_t)z * (1u << 20)) : Wot;
    __shared__ alignas(16) u16 T[64][TS];
    int r0 = blockIdx.y * 64, c0 = blockIdx.x * 64;
    int tr = threadIdx.x >> 3, tc8 = threadIdx.x & 7;
    bf16x8 v0 = load8(in, (size_t)(r0 + tr) * 1024 + c0 + tc8 * 8, f32m);
    bf16x8 v1 = load8(in, (size_t)(r0 + tr + 32) * 1024 + c0 + tc8 * 8, f32m);
    *(int4*)&T[tr][tc8 * 8]      = __builtin_bit_cast(int4, v0);
    *(int4*)&T[tr + 32][tc8 * 8] = __builtin_bit_cast(int4, v1);
    __syncthreads();
    for (int half = 0; half < 2; ++half) {
        int cr = tr + half * 32;
        u16 tmp[8];
#pragma unroll
        for (int i = 0; i < 8; ++i) tmp[i] = T[tc8 * 8 + i][cr];
        *(int4*)(out + (size_t)(c0 + cr) * 1024 + r0 + tc8 * 8) = *(int4*)tmp;
    }
}

// ---------------- 128x128-tile bf16 MFMA GEMM (QKV), XOR-swizzled LDS -------
// A: Xbf [4096][1024] bf16; Bt: Wqkv^T [3072][1024] bf16.  Pure GLD staging.
// 4 waves, each 64x64 subtile: 32 MFMA : 16 b128-reads per wave-iter.
__global__ __launch_bounds__(256, 4) void gemm128(const u16* __restrict__ A,
                                                  const u16* __restrict__ Bt,
                                                  u16* __restrict__ Cq, u16* __restrict__ Ck,
                                                  u16* __restrict__ Cv) {
    __shared__ alignas(16) u16 As[128 * 64];
    __shared__ alignas(16) u16 Bs[128 * 64];
    const int K = 1024;
    int tid = threadIdx.x, wave = tid >> 6, lane = tid & 63;
    int quad = lane >> 4, l16 = lane & 15;
    int wrow = wave >> 1, wcol = wave & 1;
    int m0 = blockIdx.x * 128, n0 = blockIdx.y * 128;
    int rlane = lane >> 3, kc = lane & 7;
    int scol = (kc ^ rlane) * 8;          // swizzled source column (u16)

    f32x4 acc[4][4] = {};

    for (int k0 = 0; k0 < K; k0 += 64) {
        __syncthreads();
#pragma unroll
        for (int i = 0; i < 4; ++i) {
            int rc = wave * 4 + i;       // 16 chunks of 8 rows each
            GLD_LDS16(A  + (size_t)(m0 + rc * 8 + rlane) * K + k0 + scol, As + rc * 512);
            GLD_LDS16(Bt + (size_t)(n0 + rc * 8 + rlane) * K + k0 + scol, Bs + rc * 512);
        }
        __syncthreads();
#pragma unroll
        for (int ks = 0; ks < 2; ++ks) {
            bf16x8 af[4], bfr[4];
#pragma unroll
            for (int i = 0; i < 4; ++i) {
                int row = wrow * 64 + i * 16 + l16;
                af[i] = as_bf16x8(*(const int4*)(As + row * 64 + (((ks * 4 + quad) ^ (row & 7)) * 8)));
            }
#pragma unroll
            for (int j = 0; j < 4; ++j) {
                int row = wcol * 64 + j * 16 + l16;
                bfr[j] = as_bf16x8(*(const int4*)(Bs + row * 64 + (((ks * 4 + quad) ^ (row & 7)) * 8)));
            }
#pragma unroll
            for (int i = 0; i < 4; ++i)
#pragma unroll
                for (int j = 0; j < 4; ++j)
                    acc[i][j] = __builtin_amdgcn_mfma_f32_16x16x32_bf16(af[i], bfr[j], acc[i][j], 0, 0, 0);
        }
    }

#pragma unroll
    for (int i = 0; i < 4; ++i)
#pragma unroll
        for (int j = 0; j < 4; ++j)
#pragma unroll
            for (int r = 0; r < 4; ++r) {
                int m = m0 + wrow * 64 + i * 16 + quad * 4 + r;
                int n = n0 + wcol * 64 + j * 16 + l16;
                float f = acc[i][j][r];
                if (n < 1024)       Cq[(size_t)m * 1024 + n] = bf16_bits(f);
                else if (n < 2048)  Ck[(size_t)m * 1024 + n - 1024] = bf16_bits(f);
                else {
                    int n2 = n - 2048;
                    int bh = ((m >> 11) << 4) | (n2 >> 6), d = n2 & 63, t = m & 2047;
                    Cv[(((size_t)bh * 64 + d) << 11) + t] = bf16_bits(f);
                }
            }
}

// ---------------- 64x128-tile GEMM (out-proj), R11-exact --------------------
__global__ __launch_bounds__(256, 4) void gemm_out(const u16* __restrict__ A,
                                                   const u16* __restrict__ Bt,
                                                   void* __restrict__ Cout,
                                                   const void* __restrict__ Xdet) {
    bool f32m = detect_f32(Xdet);
    __shared__ alignas(16) u16 As[64 * 64];
    __shared__ alignas(16) u16 Bs[128 * 64];
    const int K = 1024;
    int tid = threadIdx.x, wave = tid >> 6, lane = tid & 63;
    int quad = lane >> 4, l16 = lane & 15;
    int wrow = wave & 1, wcol = wave >> 1;
    int m0 = blockIdx.x * 64, n0 = blockIdx.y * 128;
    int rlane = lane >> 3, kc = lane & 7;
    int scol = (kc ^ rlane) * 8;

    f32x4 acc[2][4] = {};

    for (int k0 = 0; k0 < K; k0 += 64) {
        __syncthreads();
#pragma unroll
        for (int i = 0; i < 4; ++i) {
            int rc = wave * 4 + i;
            GLD_LDS16(Bt + (size_t)(n0 + rc * 8 + rlane) * K + k0 + scol, Bs + rc * 512);
        }
#pragma unroll
        for (int i = 0; i < 2; ++i) {
            int rc = wave * 2 + i;
            GLD_LDS16(A + (size_t)(m0 + rc * 8 + rlane) * K + k0 + scol, As + rc * 512);
        }
        __syncthreads();
#pragma unroll
        for (int ks = 0; ks < 2; ++ks) {
            bf16x8 af[2], bfr[4];
#pragma unroll
            for (int i = 0; i < 2; ++i) {
                int row = wrow * 32 + i * 16 + l16;
                af[i] = as_bf16x8(*(const int4*)(As + row * 64 + (((ks * 4 + quad) ^ (row & 7)) * 8)));
            }
#pragma unroll
            for (int j = 0; j < 4; ++j) {
                int row = wcol * 64 + j * 16 + l16;
                bfr[j] = as_bf16x8(*(const int4*)(Bs + row * 64 + (((ks * 4 + quad) ^ (row & 7)) * 8)));
            }
#pragma unroll
            for (int i = 0; i < 2; ++i)
#pragma unroll
                for (int j = 0; j < 4; ++j)
                    acc[i][j] = __builtin_amdgcn_mfma_f32_16x16x32_bf16(af[i], bfr[j], acc[i][j], 0, 0, 0);
        }
    }

#pragma unroll
    for (int i = 0; i < 2; ++i)
#pragma unroll
        for (int j = 0; j < 4; ++j)
#pragma unroll
            for (int r = 0; r < 4; ++r) {
                int m = m0 + wrow * 32 + i * 16 + quad * 4 + r;
                int n = n0 + wcol * 64 + j * 16 + l16;
                float f = acc[i][j][r];
                if (f32m) ((float*)Cout)[(size_t)m * 1024 + n] = f;
                else      ((u16*)Cout)[(size_t)m * 1024 + n] = bf16_bits(f);
            }
}

// ---------------- flash attention (R15: swapped QK^T, lane-local psum) ------
__global__ __launch_bounds__(512, 4) void attn_kernel(const u16* __restrict__ Qb,
                                                      const u16* __restrict__ Kb,
                                                      const u16* __restrict__ Vt,
                                                      u16* __restrict__ Ab) {
    __shared__ alignas(16) u16 Ks[128 * 64];   // swizzled [kv][d]
    __shared__ alignas(16) u16 Vs[64 * 128];   // swizzled [d][t]
    __shared__ alignas(16) u16 Ps[128 * PS];   // [q 128][kv 128] padded

    int tid = threadIdx.x, wave = tid >> 6, lane = tid & 63;
    int quad = lane >> 4, l16 = lane & 15;
    int bh = blockIdx.x;                 // x fastest => heavy-J blocks first
    // Complementary pairing: first 256 blocks J=15..8, next 256 J=0..7 ->
    // resident CU pairs (i, i+256) sum to exactly 17 kv-iters (was 24 worst).
    int J = (blockIdx.y < 8) ? (15 - (int)blockIdx.y) : ((int)blockIdx.y - 8);
    int b = bh >> 4, h = bh & 15;
    int q0 = J * 128;
    int kr4 = lane >> 3, kc = lane & 7;   // K staging: 8 rows x 8 chunks
    int vr4 = lane >> 4, vc = lane & 15;  // V staging: 4 rows x 16 chunks

    const u16* qrow = Qb + (size_t)(b * 2048 + q0 + wave * 16 + l16) * 1024 + h * 64;
    bf16x8 qa0 = as_bf16x8(*(const int4*)(qrow + quad * 8));
    bf16x8 qa1 = as_bf16x8(*(const int4*)(qrow + 32 + quad * 8));

    f32x4 o[4] = {};
    float psum = 0.0f;                   // lane-local: q = wave*16+l16 over
                                         // kv rows {nt*16+quad*4+r}

    const u16* kbase = Kb + (size_t)(b * 2048) * 1024 + h * 64;
    const u16* vbase = Vt + (size_t)bh * 64 * 2048;

    for (int j2 = 0; j2 <= J; ++j2) {
        int t0 = j2 * 128;
        __syncthreads();
#pragma unroll
        for (int i = 0; i < 2; ++i) {
            int rb = (wave * 2 + i) * 8;
            int grow = rb + kr4;
            int gch = kc ^ (grow & 7);
            GLD_LDS16(kbase + (size_t)(t0 + grow) * 1024 + gch * 8, Ks + rb * 64);
        }
#pragma unroll
        for (int i = 0; i < 2; ++i) {
            int rb = (wave * 2 + i) * 4;
            int grow = rb + vr4;
            int gch = vc ^ (grow & 15);
            GLD_LDS16(vbase + (size_t)grow * 2048 + t0 + gch * 8, Vs + rb * 128);
        }
        __syncthreads();

        bool diag = (j2 == J);
        int ntc = diag ? ((wave & ~1) + 2) : 8;

        // S^T tile: s[nt][r] = S[kv = t0+nt*16+quad*4+r][q = q0+wave*16+l16]
        f32x4 s[8];
#pragma unroll
        for (int nt = 0; nt < 8; ++nt) {
            if (nt >= ntc) continue;
            if (diag && nt > wave) {
                s[nt][0] = NEG_INF; s[nt][1] = NEG_INF; s[nt][2] = NEG_INF; s[nt][3] = NEG_INF;
                continue;
            }
            int row = nt * 16 + l16;
            int sw = row & 7;
            f32x4 a = {};
            bf16x8 b0 = as_bf16x8(*(const int4*)(Ks + row * 64 + ((quad ^ sw) * 8)));
            a = __builtin_amdgcn_mfma_f32_16x16x32_bf16(b0, qa0, a, 0, 0, 0);   // A=K, B=Q
            bf16x8 b1 = as_bf16x8(*(const int4*)(Ks + row * 64 + (((4 + quad) ^ sw) * 8)));
            a = __builtin_amdgcn_mfma_f32_16x16x32_bf16(b1, qa1, a, 0, 0, 0);
            a = a * SC_LOG2;
            if (diag && nt == wave) {
#pragma unroll
                for (int r = 0; r < 4; ++r)
                    if (quad * 4 + r > l16) a[r] = NEG_INF;
            }
            s[nt] = a;
        }

        // softmax: all lane-local.  One ds_write_b64 per nt (4 packed bf16).
        int prow = (wave * 16 + l16) * PS;
#pragma unroll
        for (int nt = 0; nt < 8; ++nt) {
            if (nt >= ntc) continue;
            u16x4 pk;
            float ps4 = 0.0f;
#pragma unroll
            for (int r = 0; r < 4; ++r) {
                float p = EXP2(s[nt][r]);
                ps4 += p;
                pk[r] = bf16_bits(p);
            }
            psum += ps4;
            *(u16x4*)(Ps + prow + nt * 16 + quad * 4) = pk;
        }

        int ksm = ntc >> 1;
#pragma unroll
        for (int ks = 0; ks < 4; ++ks) {
            if (ks >= ksm) continue;
            bf16x8 pa = as_bf16x8(*(const int4*)(Ps + (wave * 16 + l16) * PS + ks * 32 + quad * 8));
#pragma unroll
            for (int d4 = 0; d4 < 4; ++d4) {
                int vrow = d4 * 16 + l16;
                bf16x8 vb = as_bf16x8(*(const int4*)(Vs + vrow * 128 + (((ks * 4 + quad) ^ l16) * 8)));
                o[d4] = __builtin_amdgcn_mfma_f32_16x16x32_bf16(pa, vb, o[d4], 0, 0, 0);
            }
        }
    }

    // denominators: reduce across quads (kv partition), redistribute to rows.
    psum += __shfl_xor(psum, 16);
    psum += __shfl_xor(psum, 32);        // now full denom for q = wave*16+l16

    u16* arow = Ab + (size_t)(b * 2048 + q0 + wave * 16) * 1024 + h * 64;
#pragma unroll
    for (int r = 0; r < 4; ++r) {
        float dn = __shfl(psum, quad * 4 + r, 16);   // denom for q row quad*4+r
        float inv = 1.0f / dn;
#pragma unroll
        for (int d4 = 0; d4 < 4; ++d4)
            arow[(quad * 4 + r) * 1024 + d4 * 16 + l16] = bf16_bits(o[d4][r] * inv);
    }
}

// ---------------------------------------------------------------------------
extern "C" void kernel_launch(void* const* d_in, const int* in_sizes, int n_in,
                              void* d_out, int out_size, void* d_ws, size_t ws_size,
                              hipStream_t stream) {
    (void)in_sizes; (void)n_in; (void)out_size; (void)ws_size;
    const void* X  = d_in[0];
    const void* Wq = d_in[1];
    const void* Wk = d_in[2];
    const void* Wv = d_in[3];
    const void* Wo = d_in[4];
    u16* ws16 = (u16*)d_ws;
    const size_t M1 = 1u << 20;
    u16* Xbf = ws16 + 0 * M1;        // [0,4M)
    u16* Wt3 = ws16 + 4 * M1;        // [4M,7M)
    u16* Qb  = ws16 + 7 * M1;
    u16* Kb  = ws16 + 11 * M1;
    u16* Vt  = ws16 + 15 * M1;
    u16* Wot = ws16 + 19 * M1;
    u16* Ab  = ws16 + 0 * M1;        // aliases Xbf (dead after QKV GEMM)

    prep_all<<<dim3(16, 16, 5), 256, 0, stream>>>(Wq, Wk, Wv, Wo, X, Wt3, Wot, Xbf);
    gemm128<<<dim3(32, 24), 256, 0, stream>>>(Xbf, Wt3, Qb, Kb, Vt);
    attn_kernel<<<dim3(32, 16), 512, 0, stream>>>(Qb, Kb, Vt, Ab);
    gemm_out<<<dim3(64, 8), 256, 0, stream>>>(Ab, Wot, d_out, X);
}

// Round 4
// 164.948 us; speedup vs baseline: 1.2247x; 1.0379x over previous
//
#include <hip/hip_runtime.h>
#include <hip/hip_bf16.h>

// ---------------------------------------------------------------------------
// Causal MHA forward.  B=2, T=2048, H=16, Dk=64, D=1024.  Inputs float32;
// internal pipeline bf16 MFMA.
// R16: (a) gemm_out BK 64->128: 8 barrier/drain iters instead of 16, same
//     GLD count, LDS 48 KB (2 blocks/CU kept; grid caps at 2 anyway).
//     16-chunk XOR swizzle (conflict-free on 128-u16 rows).
//     (b) attn: s_setprio(1) around QK and PV MFMA clusters (T5; +4-7% on
//     attn in 2-indep-blocks/CU regime per m191; NOT applied to lockstep
//     gemms per m190).
//     R15 recap: swapped QK^T (lane-local psum) attn ~50.6 -> ~42 us.
//     prep / gemm128 frozen at R12.
//     launch_bounds min-waves MUST stay 4 (6 spilled twice: R6, R7).
// Workspace (u16 elements, 1M = 2^20), 40 MB:
//   [0,4M)   Xbf [4096][1024] bf16      (Ab aliases this after QKV)
//   [4M,7M)  Wqkv^T (3 x [1024][1024])
//   [7M,11M) Q   [11M,15M) K   [15M,19M) V^T [32][64][2048]
//   [19M,20M) Wo^T
// ---------------------------------------------------------------------------

typedef unsigned short u16;
typedef __bf16 bf16x8 __attribute__((ext_vector_type(8)));
typedef float f32x4 __attribute__((ext_vector_type(4)));
typedef u16 u16x4 __attribute__((ext_vector_type(4)));

#define TS 72               // padded LDS stride (transpose)
#define PS 136              // P-tile LDS stride (R5-proven)
#define NEG_INF (-1e30f)
#define SC_LOG2 0.1803368801f   // log2(e)/8  (exp2-domain softmax scale)

#if __has_builtin(__builtin_amdgcn_exp2f)
#define EXP2(x) __builtin_amdgcn_exp2f(x)
#else
#define EXP2(x) exp2f(x)
#endif

#define GLD_LDS16(gp, lp) __builtin_amdgcn_global_load_lds( \
    (const __attribute__((address_space(1))) void*)(gp),    \
    (__attribute__((address_space(3))) void*)(lp), 16, 0, 0)

__device__ __forceinline__ bf16x8 as_bf16x8(int4 v) { return __builtin_bit_cast(bf16x8, v); }
__device__ __forceinline__ u16 bf16_bits(float f) { return __builtin_bit_cast(u16, (__bf16)f); }

// Runtime dtype detect: f32-as-u16 low words have big exponent fields.
__device__ __forceinline__ bool detect_f32(const void* X) {
    const u16* x16 = (const u16*)X;
    int lane = threadIdx.x & 63;
    int hits = 0;
#pragma unroll
    for (int i = 0; i < 4; ++i) {
        u16 v = x16[lane * 4 + i];
        hits += (((v >> 7) & 0xFF) > 130) ? 1 : 0;
    }
    return __popcll(__ballot(hits > 0)) >= 8;
}

__device__ __forceinline__ bf16x8 load8(const void* p, size_t eoff, bool f32m) {
    if (!f32m) return as_bf16x8(*(const int4*)((const u16*)p + eoff));
    const float* f = (const float*)p + eoff;
    float4 a = *(const float4*)f;
    float4 b = *(const float4*)(f + 4);
    bf16x8 r;
    r[0] = (__bf16)a.x; r[1] = (__bf16)a.y; r[2] = (__bf16)a.z; r[3] = (__bf16)a.w;
    r[4] = (__bf16)b.x; r[5] = (__bf16)b.y; r[6] = (__bf16)b.z; r[7] = (__bf16)b.w;
    return r;
}

// ---------------- prep: 4 weight transposes (z=0..3) + X cvt (z=4) ----------
__global__ __launch_bounds__(256) void prep_all(const void* __restrict__ Wq,
                                                const void* __restrict__ Wk,
                                                const void* __restrict__ Wv,
                                                const void* __restrict__ Wo,
                                                const void* __restrict__ X,
                                                u16* __restrict__ Wt3,
                                                u16* __restrict__ Wot,
                                                u16* __restrict__ Xbf) {
    bool f32m = detect_f32(X);
    int z = blockIdx.z;
    if (z == 4) {
        int blk = blockIdx.y * 16 + blockIdx.x;
        size_t base = (size_t)blk * 16384 + threadIdx.x * 8;
#pragma unroll
        for (int i = 0; i < 8; ++i) {
            size_t eoff = base + (size_t)i * 2048;
            bf16x8 v = load8(X, eoff, f32m);
            *(int4*)(Xbf + eoff) = __builtin_bit_cast(int4, v);
        }
        return;
    }
    const void* in = (z == 0) ? Wq : (z == 1) ? Wk : (z == 2) ? Wv : Wo;
    u16* out = (z < 3) ? (Wt3 + (size_t)z * (1u << 20)) : Wot;
    __shared__ alignas(16) u16 T[64][TS];
    int r0 = blockIdx.y * 64, c0 = blockIdx.x * 64;
    int tr = threadIdx.x >> 3, tc8 = threadIdx.x & 7;
    bf16x8 v0 = load8(in, (size_t)(r0 + tr) * 1024 + c0 + tc8 * 8, f32m);
    bf16x8 v1 = load8(in, (size_t)(r0 + tr + 32) * 1024 + c0 + tc8 * 8, f32m);
    *(int4*)&T[tr][tc8 * 8]      = __builtin_bit_cast(int4, v0);
    *(int4*)&T[tr + 32][tc8 * 8] = __builtin_bit_cast(int4, v1);
    __syncthreads();
    for (int half = 0; half < 2; ++half) {
        int cr = tr + half * 32;
        u16 tmp[8];
#pragma unroll
        for (int i = 0; i < 8; ++i) tmp[i] = T[tc8 * 8 + i][cr];
        *(int4*)(out + (size_t)(c0 + cr) * 1024 + r0 + tc8 * 8) = *(int4*)tmp;
    }
}

// ---------------- 128x128-tile bf16 MFMA GEMM (QKV), XOR-swizzled LDS -------
// A: Xbf [4096][1024] bf16; Bt: Wqkv^T [3072][1024] bf16.  Pure GLD staging.
// 4 waves, each 64x64 subtile: 32 MFMA : 16 b128-reads per wave-iter.
__global__ __launch_bounds__(256, 4) void gemm128(const u16* __restrict__ A,
                                                  const u16* __restrict__ Bt,
                                                  u16* __restrict__ Cq, u16* __restrict__ Ck,
                                                  u16* __restrict__ Cv) {
    __shared__ alignas(16) u16 As[128 * 64];
    __shared__ alignas(16) u16 Bs[128 * 64];
    const int K = 1024;
    int tid = threadIdx.x, wave = tid >> 6, lane = tid & 63;
    int quad = lane >> 4, l16 = lane & 15;
    int wrow = wave >> 1, wcol = wave & 1;
    int m0 = blockIdx.x * 128, n0 = blockIdx.y * 128;
    int rlane = lane >> 3, kc = lane & 7;
    int scol = (kc ^ rlane) * 8;          // swizzled source column (u16)

    f32x4 acc[4][4] = {};

    for (int k0 = 0; k0 < K; k0 += 64) {
        __syncthreads();
#pragma unroll
        for (int i = 0; i < 4; ++i) {
            int rc = wave * 4 + i;       // 16 chunks of 8 rows each
            GLD_LDS16(A  + (size_t)(m0 + rc * 8 + rlane) * K + k0 + scol, As + rc * 512);
            GLD_LDS16(Bt + (size_t)(n0 + rc * 8 + rlane) * K + k0 + scol, Bs + rc * 512);
        }
        __syncthreads();
#pragma unroll
        for (int ks = 0; ks < 2; ++ks) {
            bf16x8 af[4], bfr[4];
#pragma unroll
            for (int i = 0; i < 4; ++i) {
                int row = wrow * 64 + i * 16 + l16;
                af[i] = as_bf16x8(*(const int4*)(As + row * 64 + (((ks * 4 + quad) ^ (row & 7)) * 8)));
            }
#pragma unroll
            for (int j = 0; j < 4; ++j) {
                int row = wcol * 64 + j * 16 + l16;
                bfr[j] = as_bf16x8(*(const int4*)(Bs + row * 64 + (((ks * 4 + quad) ^ (row & 7)) * 8)));
            }
#pragma unroll
            for (int i = 0; i < 4; ++i)
#pragma unroll
                for (int j = 0; j < 4; ++j)
                    acc[i][j] = __builtin_amdgcn_mfma_f32_16x16x32_bf16(af[i], bfr[j], acc[i][j], 0, 0, 0);
        }
    }

#pragma unroll
    for (int i = 0; i < 4; ++i)
#pragma unroll
        for (int j = 0; j < 4; ++j)
#pragma unroll
            for (int r = 0; r < 4; ++r) {
                int m = m0 + wrow * 64 + i * 16 + quad * 4 + r;
                int n = n0 + wcol * 64 + j * 16 + l16;
                float f = acc[i][j][r];
                if (n < 1024)       Cq[(size_t)m * 1024 + n] = bf16_bits(f);
                else if (n < 2048)  Ck[(size_t)m * 1024 + n - 1024] = bf16_bits(f);
                else {
                    int n2 = n - 2048;
                    int bh = ((m >> 11) << 4) | (n2 >> 6), d = n2 & 63, t = m & 2047;
                    Cv[(((size_t)bh * 64 + d) << 11) + t] = bf16_bits(f);
                }
            }
}

// ---------------- 64x128-tile GEMM (out-proj), R16: BK=128 ------------------
// 8 staging iterations (was 16): halves barrier + vmcnt(0)-drain count.
// 16-chunk XOR swizzle on 128-u16 rows: 16 distinct l16 rows -> 16 distinct
// bank groups on ds_read_b128 (conflict-free).
__global__ __launch_bounds__(256, 4) void gemm_out(const u16* __restrict__ A,
                                                   const u16* __restrict__ Bt,
                                                   void* __restrict__ Cout,
                                                   const void* __restrict__ Xdet) {
    bool f32m = detect_f32(Xdet);
    __shared__ alignas(16) u16 As[64 * 128];    // 16 KB
    __shared__ alignas(16) u16 Bs[128 * 128];   // 32 KB
    const int K = 1024;
    int tid = threadIdx.x, wave = tid >> 6, lane = tid & 63;
    int quad = lane >> 4, l16 = lane & 15;
    int wrow = wave & 1, wcol = wave >> 1;
    int m0 = blockIdx.x * 64, n0 = blockIdx.y * 128;
    int rlane4 = lane >> 4, kc16 = lane & 15;   // staging: 4 rows x 16 chunks

    f32x4 acc[2][4] = {};

    for (int k0 = 0; k0 < K; k0 += 128) {
        __syncthreads();
#pragma unroll
        for (int i = 0; i < 8; ++i) {           // B: 128 rows, 4 per GLD
            int rb = wave * 32 + i * 4;
            int grow = rb + rlane4;
            int gch = kc16 ^ (grow & 15);
            GLD_LDS16(Bt + (size_t)(n0 + grow) * K + k0 + gch * 8, Bs + rb * 128);
        }
#pragma unroll
        for (int i = 0; i < 4; ++i) {           // A: 64 rows, 4 per GLD
            int rb = wave * 16 + i * 4;
            int grow = rb + rlane4;
            int gch = kc16 ^ (grow & 15);
            GLD_LDS16(A + (size_t)(m0 + grow) * K + k0 + gch * 8, As + rb * 128);
        }
        __syncthreads();
#pragma unroll
        for (int ks = 0; ks < 4; ++ks) {
            bf16x8 af[2], bfr[4];
#pragma unroll
            for (int i = 0; i < 2; ++i) {
                int row = wrow * 32 + i * 16 + l16;
                af[i] = as_bf16x8(*(const int4*)(As + row * 128 + (((ks * 4 + quad) ^ (row & 15)) * 8)));
            }
#pragma unroll
            for (int j = 0; j < 4; ++j) {
                int row = wcol * 64 + j * 16 + l16;
                bfr[j] = as_bf16x8(*(const int4*)(Bs + row * 128 + (((ks * 4 + quad) ^ (row & 15)) * 8)));
            }
#pragma unroll
            for (int i = 0; i < 2; ++i)
#pragma unroll
                for (int j = 0; j < 4; ++j)
                    acc[i][j] = __builtin_amdgcn_mfma_f32_16x16x32_bf16(af[i], bfr[j], acc[i][j], 0, 0, 0);
        }
    }

#pragma unroll
    for (int i = 0; i < 2; ++i)
#pragma unroll
        for (int j = 0; j < 4; ++j)
#pragma unroll
            for (int r = 0; r < 4; ++r) {
                int m = m0 + wrow * 32 + i * 16 + quad * 4 + r;
                int n = n0 + wcol * 64 + j * 16 + l16;
                float f = acc[i][j][r];
                if (f32m) ((float*)Cout)[(size_t)m * 1024 + n] = f;
                else      ((u16*)Cout)[(size_t)m * 1024 + n] = bf16_bits(f);
            }
}

// ---------------- flash attention (R15 + T5 setprio) ------------------------
__global__ __launch_bounds__(512, 4) void attn_kernel(const u16* __restrict__ Qb,
                                                      const u16* __restrict__ Kb,
                                                      const u16* __restrict__ Vt,
                                                      u16* __restrict__ Ab) {
    __shared__ alignas(16) u16 Ks[128 * 64];   // swizzled [kv][d]
    __shared__ alignas(16) u16 Vs[64 * 128];   // swizzled [d][t]
    __shared__ alignas(16) u16 Ps[128 * PS];   // [q 128][kv 128] padded

    int tid = threadIdx.x, wave = tid >> 6, lane = tid & 63;
    int quad = lane >> 4, l16 = lane & 15;
    int bh = blockIdx.x;                 // x fastest => heavy-J blocks first
    // Complementary pairing: first 256 blocks J=15..8, next 256 J=0..7 ->
    // resident CU pairs (i, i+256) sum to exactly 17 kv-iters (was 24 worst).
    int J = (blockIdx.y < 8) ? (15 - (int)blockIdx.y) : ((int)blockIdx.y - 8);
    int b = bh >> 4, h = bh & 15;
    int q0 = J * 128;
    int kr4 = lane >> 3, kc = lane & 7;   // K staging: 8 rows x 8 chunks
    int vr4 = lane >> 4, vc = lane & 15;  // V staging: 4 rows x 16 chunks

    const u16* qrow = Qb + (size_t)(b * 2048 + q0 + wave * 16 + l16) * 1024 + h * 64;
    bf16x8 qa0 = as_bf16x8(*(const int4*)(qrow + quad * 8));
    bf16x8 qa1 = as_bf16x8(*(const int4*)(qrow + 32 + quad * 8));

    f32x4 o[4] = {};
    float psum = 0.0f;                   // lane-local: q = wave*16+l16 over
                                         // kv rows {nt*16+quad*4+r}

    const u16* kbase = Kb + (size_t)(b * 2048) * 1024 + h * 64;
    const u16* vbase = Vt + (size_t)bh * 64 * 2048;

    for (int j2 = 0; j2 <= J; ++j2) {
        int t0 = j2 * 128;
        __syncthreads();
#pragma unroll
        for (int i = 0; i < 2; ++i) {
            int rb = (wave * 2 + i) * 8;
            int grow = rb + kr4;
            int gch = kc ^ (grow & 7);
            GLD_LDS16(kbase + (size_t)(t0 + grow) * 1024 + gch * 8, Ks + rb * 64);
        }
#pragma unroll
        for (int i = 0; i < 2; ++i) {
            int rb = (wave * 2 + i) * 4;
            int grow = rb + vr4;
            int gch = vc ^ (grow & 15);
            GLD_LDS16(vbase + (size_t)grow * 2048 + t0 + gch * 8, Vs + rb * 128);
        }
        __syncthreads();

        bool diag = (j2 == J);
        int ntc = diag ? ((wave & ~1) + 2) : 8;

        // S^T tile: s[nt][r] = S[kv = t0+nt*16+quad*4+r][q = q0+wave*16+l16]
        f32x4 s[8];
        __builtin_amdgcn_s_setprio(1);
#pragma unroll
        for (int nt = 0; nt < 8; ++nt) {
            if (nt >= ntc) continue;
            if (diag && nt > wave) {
                s[nt][0] = NEG_INF; s[nt][1] = NEG_INF; s[nt][2] = NEG_INF; s[nt][3] = NEG_INF;
                continue;
            }
            int row = nt * 16 + l16;
            int sw = row & 7;
            f32x4 a = {};
            bf16x8 b0 = as_bf16x8(*(const int4*)(Ks + row * 64 + ((quad ^ sw) * 8)));
            a = __builtin_amdgcn_mfma_f32_16x16x32_bf16(b0, qa0, a, 0, 0, 0);   // A=K, B=Q
            bf16x8 b1 = as_bf16x8(*(const int4*)(Ks + row * 64 + (((4 + quad) ^ sw) * 8)));
            a = __builtin_amdgcn_mfma_f32_16x16x32_bf16(b1, qa1, a, 0, 0, 0);
            a = a * SC_LOG2;
            if (diag && nt == wave) {
#pragma unroll
                for (int r = 0; r < 4; ++r)
                    if (quad * 4 + r > l16) a[r] = NEG_INF;
            }
            s[nt] = a;
        }
        __builtin_amdgcn_s_setprio(0);

        // softmax: all lane-local.  One ds_write_b64 per nt (4 packed bf16).
        int prow = (wave * 16 + l16) * PS;
#pragma unroll
        for (int nt = 0; nt < 8; ++nt) {
            if (nt >= ntc) continue;
            u16x4 pk;
            float ps4 = 0.0f;
#pragma unroll
            for (int r = 0; r < 4; ++r) {
                float p = EXP2(s[nt][r]);
                ps4 += p;
                pk[r] = bf16_bits(p);
            }
            psum += ps4;
            *(u16x4*)(Ps + prow + nt * 16 + quad * 4) = pk;
        }

        int ksm = ntc >> 1;
        __builtin_amdgcn_s_setprio(1);
#pragma unroll
        for (int ks = 0; ks < 4; ++ks) {
            if (ks >= ksm) continue;
            bf16x8 pa = as_bf16x8(*(const int4*)(Ps + (wave * 16 + l16) * PS + ks * 32 + quad * 8));
#pragma unroll
            for (int d4 = 0; d4 < 4; ++d4) {
                int vrow = d4 * 16 + l16;
                bf16x8 vb = as_bf16x8(*(const int4*)(Vs + vrow * 128 + (((ks * 4 + quad) ^ l16) * 8)));
                o[d4] = __builtin_amdgcn_mfma_f32_16x16x32_bf16(pa, vb, o[d4], 0, 0, 0);
            }
        }
        __builtin_amdgcn_s_setprio(0);
    }

    // denominators: reduce across quads (kv partition), redistribute to rows.
    psum += __shfl_xor(psum, 16);
    psum += __shfl_xor(psum, 32);        // now full denom for q = wave*16+l16

    u16* arow = Ab + (size_t)(b * 2048 + q0 + wave * 16) * 1024 + h * 64;
#pragma unroll
    for (int r = 0; r < 4; ++r) {
        float dn = __shfl(psum, quad * 4 + r, 16);   // denom for q row quad*4+r
        float inv = 1.0f / dn;
#pragma unroll
        for (int d4 = 0; d4 < 4; ++d4)
            arow[(quad * 4 + r) * 1024 + d4 * 16 + l16] = bf16_bits(o[d4][r] * inv);
    }
}

// ---------------------------------------------------------------------------
extern "C" void kernel_launch(void* const* d_in, const int* in_sizes, int n_in,
                              void* d_out, int out_size, void* d_ws, size_t ws_size,
                              hipStream_t stream) {
    (void)in_sizes; (void)n_in; (void)out_size; (void)ws_size;
    const void* X  = d_in[0];
    const void* Wq = d_in[1];
    const void* Wk = d_in[2];
    const void* Wv = d_in[3];
    const void* Wo = d_in[4];
    u16* ws16 = (u16*)d_ws;
    const size_t M1 = 1u << 20;
    u16* Xbf = ws16 + 0 * M1;        // [0,4M)
    u16* Wt3 = ws16 + 4 * M1;        // [4M,7M)
    u16* Qb  = ws16 + 7 * M1;
    u16* Kb  = ws16 + 11 * M1;
    u16* Vt  = ws16 + 15 * M1;
    u16* Wot = ws16 + 19 * M1;
    u16* Ab  = ws16 + 0 * M1;        // aliases Xbf (dead after QKV GEMM)

    prep_all<<<dim3(16, 16, 5), 256, 0, stream>>>(Wq, Wk, Wv, Wo, X, Wt3, Wot, Xbf);
    gemm128<<<dim3(32, 24), 256, 0, stream>>>(Xbf, Wt3, Qb, Kb, Vt);
    attn_kernel<<<dim3(32, 16), 512, 0, stream>>>(Qb, Kb, Vt, Ab);
    gemm_out<<<dim3(64, 8), 256, 0, stream>>>(Ab, Wot, d_out, X);
}